// Round 1
// baseline (3472.315 us; speedup 1.0000x reference)
//
#include <hip/hip_runtime.h>
#include <math.h>

// Problem constants (from reference)
#define BB 2
#define TT 2048
#define DD 2048
#define EE 8
#define CC 512
#define OO1 256   // D / E

// Tile config
#define BM 64
#define BN 64
#define BK 16
#define PAD 4   // LDS pad (stride 68 -> 2-way max conflict, keeps 16B alignment)

// Generic batched strided SGEMM: C[z][m][n] = sum_k A[m][k]*B[k][n]  (+epilogue)
// Batch base offsets: base = (z / mod)*hi + (z % mod)*lo
// EPI: 0 = none, 1 = +bias[n] then exact GELU, 2 = +bias[n]
template<int EPI>
__global__ __launch_bounds__(256)
void gemm_kernel(const float* __restrict__ A, long sAm, long sAk,
                 long bsAhi, long bsAlo, int modA,
                 const float* __restrict__ B, long sBk, long sBn,
                 long bsBhi, long bsBlo, int modB,
                 float* __restrict__ C,
                 const float* __restrict__ bias, long bsBiasLo, int modBias,
                 int M, int N, int K)
{
    __shared__ float As[BK][BM + PAD];
    __shared__ float Bs[BK][BN + PAD];

    const int z = blockIdx.z;
    const float* Ab = A + (long)(z / modA) * bsAhi + (long)(z % modA) * bsAlo;
    const float* Bb = B + (long)(z / modB) * bsBhi + (long)(z % modB) * bsBlo;
    float* Cb = C + (long)z * (long)M * (long)N;
    const float* biasB = nullptr;
    if (EPI != 0) biasB = bias + (long)(z % modBias) * bsBiasLo;

    const int tid = threadIdx.x;
    const int tx = tid & 15;
    const int ty = tid >> 4;
    const int m0 = blockIdx.y * BM;
    const int n0 = blockIdx.x * BN;

    const bool aKinner = (sAk == 1);
    const bool bNinner = (sBn == 1);

    float acc[4][4];
    #pragma unroll
    for (int i = 0; i < 4; ++i)
        #pragma unroll
        for (int j = 0; j < 4; ++j) acc[i][j] = 0.0f;

    for (int k0 = 0; k0 < K; k0 += BK) {
        // ---- stage A tile: As[k][m] ----
        if (aKinner) {
            // A row-major [M][K]: consecutive tid -> consecutive k (coalesced)
            #pragma unroll
            for (int i = tid; i < BM * BK; i += 256) {
                int m = i >> 4;       // i / BK
                int k = i & 15;       // i % BK
                As[k][m] = Ab[(long)(m0 + m) * sAm + (long)(k0 + k)];
            }
        } else {
            // A stored [K][M]-ish (sAm==1): consecutive tid -> consecutive m
            #pragma unroll
            for (int i = tid; i < BM * BK; i += 256) {
                int k = i >> 6;       // i / BM
                int m = i & 63;       // i % BM
                As[k][m] = Ab[(long)(m0 + m) * sAm + (long)(k0 + k) * sAk];
            }
        }
        // ---- stage B tile: Bs[k][n] ----
        if (bNinner) {
            #pragma unroll
            for (int i = tid; i < BK * BN; i += 256) {
                int k = i >> 6;       // i / BN
                int n = i & 63;       // i % BN
                Bs[k][n] = Bb[(long)(k0 + k) * sBk + (long)(n0 + n)];
            }
        } else {
            // B stored [N][K] (sBk==1): consecutive tid -> consecutive k
            #pragma unroll
            for (int i = tid; i < BK * BN; i += 256) {
                int n = i >> 4;       // i / BK
                int k = i & 15;       // i % BK
                Bs[k][n] = Bb[(long)(k0 + k) * sBk + (long)(n0 + n) * sBn];
            }
        }
        __syncthreads();

        // ---- compute 4x4 micro-tile ----
        #pragma unroll
        for (int k = 0; k < BK; ++k) {
            float4 a4 = *(const float4*)&As[k][ty * 4];
            float4 b4 = *(const float4*)&Bs[k][tx * 4];
            float av[4] = {a4.x, a4.y, a4.z, a4.w};
            float bv[4] = {b4.x, b4.y, b4.z, b4.w};
            #pragma unroll
            for (int i = 0; i < 4; ++i)
                #pragma unroll
                for (int j = 0; j < 4; ++j)
                    acc[i][j] += av[i] * bv[j];
        }
        __syncthreads();
    }

    // ---- epilogue + store (vectorized float4 rows) ----
    #pragma unroll
    for (int i = 0; i < 4; ++i) {
        long m = m0 + ty * 4 + i;
        float out4[4];
        #pragma unroll
        for (int j = 0; j < 4; ++j) {
            int n = n0 + tx * 4 + j;
            float v = acc[i][j];
            if (EPI == 1) {
                v += biasB[n];
                v = 0.5f * v * (1.0f + erff(v * 0.70710678118654752f));
            } else if (EPI == 2) {
                v += biasB[n];
            }
            out4[j] = v;
        }
        *(float4*)&Cb[m * (long)N + (n0 + tx * 4)] = *(float4*)out4;
    }
}

extern "C" void kernel_launch(void* const* d_in, const int* in_sizes, int n_in,
                              void* d_out, int out_size, void* d_ws, size_t ws_size,
                              hipStream_t stream) {
    const float* x    = (const float*)d_in[0];  // [B,T,D]
    const float* mask = (const float*)d_in[1];  // [B,T,E,C]
    const float* comb = (const float*)d_in[2];  // [B,T,E,C]
    const float* W1   = (const float*)d_in[3];  // [E,O1,D]
    const float* b1   = (const float*)d_in[4];  // [E,O1]
    const float* W2   = (const float*)d_in[5];  // [E,D,O1]
    const float* b2   = (const float*)d_in[6];  // [D]
    float* out = (float*)d_out;                 // [B,T,D]

    // workspace layout (fp32): xe [B*E, C, D] | h [B*E, C, O1] | y [B*E, C, D]
    float* ws = (float*)d_ws;
    float* xe = ws;                                   // 16,777,216 floats
    float* h  = ws + 16777216L;                       //  2,097,152 floats
    float* y  = ws + 16777216L + 2097152L;            // 16,777,216 floats

    const long TEC = (long)TT * EE * CC;   // 8,388,608
    const long TD  = (long)TT * DD;        // 4,194,304
    const long ECD = (long)EE * CC * DD;   // 8,388,608

    dim3 blk(256);

    // GEMM1: xe[z=(b,e)][c][d] = sum_t mask[b,t,e,c] * x[b,t,d]
    // M=C=512, N=D=2048, K=T=2048
    gemm_kernel<0><<<dim3(DD / BN, CC / BM, BB * EE), blk, 0, stream>>>(
        mask, /*sAm=*/1L, /*sAk=*/(long)EE * CC, /*hi=*/TEC, /*lo=*/(long)CC, /*modA=*/EE,
        x,    /*sBk=*/(long)DD, /*sBn=*/1L,      /*hi=*/TD,  /*lo=*/0L,       /*modB=*/EE,
        xe, nullptr, 0L, 1,
        CC, DD, TT);

    // GEMM2: h[z][c][o] = sum_d xe[z][c][d] * W1[e,o,d] + b1[e,o], GELU
    // M=512, N=O1=256, K=D=2048
    gemm_kernel<1><<<dim3(OO1 / BN, CC / BM, BB * EE), blk, 0, stream>>>(
        xe, /*sAm=*/(long)DD, /*sAk=*/1L, /*hi=*/(long)CC * DD, /*lo=*/0L, /*modA=*/1,
        W1, /*sBk=*/1L, /*sBn=*/(long)DD, /*hi=*/0L, /*lo=*/(long)OO1 * DD, /*modB=*/EE,
        h, b1, /*bsBiasLo=*/(long)OO1, /*modBias=*/EE,
        CC, OO1, DD);

    // GEMM3: y[z][c][o] = sum_i h[z][c][i] * W2[e,o,i] + b2[o]
    // M=512, N=D=2048, K=O1=256
    gemm_kernel<2><<<dim3(DD / BN, CC / BM, BB * EE), blk, 0, stream>>>(
        h,  /*sAm=*/(long)OO1, /*sAk=*/1L, /*hi=*/(long)CC * OO1, /*lo=*/0L, /*modA=*/1,
        W2, /*sBk=*/1L, /*sBn=*/(long)OO1, /*hi=*/0L, /*lo=*/(long)DD * OO1, /*modB=*/EE,
        y, b2, /*bsBiasLo=*/0L, /*modBias=*/1,
        CC, DD, OO1);

    // GEMM4: out[b][t][o] = sum_{ec} comb[b,t,e,c] * y[b][ec][o]
    // M=T=2048, N=D=2048, K=E*C=4096
    gemm_kernel<0><<<dim3(DD / BN, TT / BM, BB), blk, 0, stream>>>(
        comb, /*sAm=*/(long)EE * CC, /*sAk=*/1L, /*hi=*/TEC, /*lo=*/0L, /*modA=*/1,
        y,    /*sBk=*/(long)DD, /*sBn=*/1L,      /*hi=*/ECD, /*lo=*/0L, /*modB=*/1,
        out, nullptr, 0L, 1,
        TT, DD, (long)EE * CC);
}

// Round 2
// 306.917 us; speedup vs baseline: 11.3135x; 11.3135x over previous
//
#include <hip/hip_runtime.h>
#include <math.h>

#define BB 2
#define TT 2048
#define DD 2048
#define EE 8
#define CCv 512
#define OO1 256

typedef unsigned short u16;
typedef __bf16 bf16x8 __attribute__((ext_vector_type(8)));
typedef float f32x4 __attribute__((ext_vector_type(4)));

__device__ __forceinline__ u16 f2bf(float f) {
    unsigned u = __float_as_uint(f);
    unsigned r = (u + 0x7fffu + ((u >> 16) & 1u)) >> 16;
    return (u16)r;
}

__device__ __forceinline__ void gload16(const void* g, void* s) {
    __builtin_amdgcn_global_load_lds(
        (const __attribute__((address_space(1))) void*)g,
        (__attribute__((address_space(3))) void*)s, 16, 0, 0);
}

// ---------------- fp32 -> bf16 straight convert (vectorized) ----------------
__global__ __launch_bounds__(256) void conv_cast(const float* __restrict__ in,
                                                 u16* __restrict__ out, long n) {
    long i = ((long)blockIdx.x * 256 + threadIdx.x) * 4;
    if (i + 3 >= n + 4) { }
    float4 v = *(const float4*)&in[i];
    u16 o0 = f2bf(v.x), o1 = f2bf(v.y), o2 = f2bf(v.z), o3 = f2bf(v.w);
    ushort4 o; o.x = o0; o.y = o1; o.z = o2; o.w = o3;
    *(ushort4*)&out[i] = o;
}

// ---------------- tiled transpose + convert: out[z][c][t] = in[z][t][c] ----------------
// in element [t][c] at inBase(z) + t*sIn + c ; out element at out + z*outZ + c*sOut + t
__global__ __launch_bounds__(256) void transpose_conv(
    const float* __restrict__ in, long inHi, long inLo, int modZ, long sIn,
    u16* __restrict__ out, long outZ, long sOut)
{
    __shared__ float tile[32][33];
    const int z = blockIdx.z;
    const float* ib = in + (long)(z / modZ) * inHi + (long)(z % modZ) * inLo;
    u16* ob = out + (long)z * outZ;
    const int t0 = blockIdx.y * 32, c0 = blockIdx.x * 32;
    const int tid = threadIdx.x;
    const int r = tid >> 3, c4 = (tid & 7) * 4;

    float4 v = *(const float4*)&ib[(long)(t0 + r) * sIn + c0 + c4];
    tile[r][c4 + 0] = v.x; tile[r][c4 + 1] = v.y;
    tile[r][c4 + 2] = v.z; tile[r][c4 + 3] = v.w;
    __syncthreads();

    const int oc = tid >> 3, t4 = (tid & 7) * 4;
    ushort4 o;
    o.x = f2bf(tile[t4 + 0][oc]);
    o.y = f2bf(tile[t4 + 1][oc]);
    o.z = f2bf(tile[t4 + 2][oc]);
    o.w = f2bf(tile[t4 + 3][oc]);
    *(ushort4*)&ob[(long)(c0 + oc) * sOut + t0 + t4] = o;
}

// ---------------- generic batched bf16 MFMA GEMM ----------------
// C[z][m][n] = sum_k A[z][m][k] * B[z][n][k]   (A: [M][K], B: [N][K], both K-contiguous)
// batch base (elems): base = (z/mod)*Hi + (z%mod)*Lo ; output row stride ldC
// EPI: 0 none, 1 col-bias + exact GELU, 3 row-bias. OUTBF: 1 -> bf16 out, 0 -> fp32 out.
template<int EPI, int OUTBF>
__global__ __launch_bounds__(256)
void mfma_gemm(const u16* __restrict__ A, long ldA, long aHi, long aLo, int modA,
               const u16* __restrict__ B, long ldB, long bHi, long bLo, int modB,
               void* __restrict__ Cout, long ldC, long cHi, long cLo, int modC,
               const float* __restrict__ bias, long biasLo, int modBias,
               int M, int N, int K)
{
    __shared__ char smem[32768];
    char* smA = smem;
    char* smB = smem + 16384;

    const int z = blockIdx.z;
    const char* Ab = (const char*)(A + (long)(z / modA) * aHi + (long)(z % modA) * aLo);
    const char* Bb = (const char*)(B + (long)(z / modB) * bHi + (long)(z % modB) * bLo);
    const long ldAb = ldA * 2, ldBb = ldB * 2;

    const int m0 = blockIdx.y * 128, n0 = blockIdx.x * 128;
    const int tid = threadIdx.x;
    const int l = tid & 63;
    const int w = tid >> 6;          // wave 0..3
    const int wm = w >> 1, wn = w & 1;

    // staging constants: lane l stages chunk (row = l>>3 within 8-row group, col l&7),
    // pre-swizzled source chunk = (l&7) ^ (l>>3)  [XOR-involution, T2]
    const int srow = l >> 3;
    const int schunk = (l & 7) ^ srow;
    // fragment constants
    const int frow = l & 15;
    const int fgrp = l >> 4;
    const int fch0 = fgrp ^ (l & 7); // swizzled k-chunk for kk=0 (row&7 == l&7)

    int aoff[4], boff[4];
#pragma unroll
    for (int i = 0; i < 4; ++i) {
        aoff[i] = (wm * 64 + i * 16 + frow) * 128 + fch0 * 16;
        boff[i] = (wn * 64 + i * 16 + frow) * 128 + fch0 * 16;
    }

    f32x4 acc[4][4];
    const f32x4 zero4 = {0.f, 0.f, 0.f, 0.f};
#pragma unroll
    for (int i = 0; i < 4; ++i)
#pragma unroll
        for (int j = 0; j < 4; ++j) acc[i][j] = zero4;

    const long sgo = (long)schunk * 16;

    for (int k0 = 0; k0 < K; k0 += 64) {
        const long kb = (long)k0 * 2;
#pragma unroll
        for (int j = 0; j < 4; ++j) {
            const int rr = (j * 4 + w) * 8 + srow;
            gload16(Ab + (long)(m0 + rr) * ldAb + kb + sgo, smA + (j * 4 + w) * 1024);
            gload16(Bb + (long)(n0 + rr) * ldBb + kb + sgo, smB + (j * 4 + w) * 1024);
        }
        __syncthreads();
#pragma unroll
        for (int kk = 0; kk < 2; ++kk) {
            const int kx = kk * 64;
            bf16x8 af[4], bfr[4];
#pragma unroll
            for (int i = 0; i < 4; ++i) af[i] = *(const bf16x8*)(smA + (aoff[i] ^ kx));
#pragma unroll
            for (int i = 0; i < 4; ++i) bfr[i] = *(const bf16x8*)(smB + (boff[i] ^ kx));
#pragma unroll
            for (int mi = 0; mi < 4; ++mi)
#pragma unroll
                for (int ni = 0; ni < 4; ++ni)
                    acc[mi][ni] = __builtin_amdgcn_mfma_f32_16x16x32_bf16(
                        af[mi], bfr[ni], acc[mi][ni], 0, 0, 0);
        }
        __syncthreads();
    }

    // epilogue: C/D layout col = lane&15, row = (lane>>4)*4 + reg  [m89-verified]
    const long cbase = (long)(z / modC) * cHi + (long)(z % modC) * cLo;
    const float* biasB = (EPI != 0) ? (bias + (long)(z % modBias) * biasLo) : nullptr;
#pragma unroll
    for (int mi = 0; mi < 4; ++mi) {
#pragma unroll
        for (int ni = 0; ni < 4; ++ni) {
            const int col = n0 + wn * 64 + ni * 16 + frow;
            const int rowb = m0 + wm * 64 + mi * 16 + fgrp * 4;
#pragma unroll
            for (int r = 0; r < 4; ++r) {
                float v = acc[mi][ni][r];
                const int row = rowb + r;
                if (EPI == 1) {
                    v += biasB[col];
                    v = 0.5f * v * (1.0f + erff(v * 0.70710678118654752f));
                } else if (EPI == 3) {
                    v += biasB[row];
                }
                const long idx = cbase + (long)row * ldC + col;
                if (OUTBF) ((u16*)Cout)[idx] = f2bf(v);
                else       ((float*)Cout)[idx] = v;
            }
        }
    }
}

extern "C" void kernel_launch(void* const* d_in, const int* in_sizes, int n_in,
                              void* d_out, int out_size, void* d_ws, size_t ws_size,
                              hipStream_t stream) {
    const float* x    = (const float*)d_in[0];  // [B,T,D]
    const float* mask = (const float*)d_in[1];  // [B,T,E,C]
    const float* comb = (const float*)d_in[2];  // [B,T,E,C]
    const float* W1   = (const float*)d_in[3];  // [E,O1,D]
    const float* b1   = (const float*)d_in[4];  // [E,O1]
    const float* W2   = (const float*)d_in[5];  // [E,D,O1]
    const float* b2   = (const float*)d_in[6];  // [D]
    float* out = (float*)d_out;                 // [B,T,D]

    // ws layout (bytes), total 104,857,600:
    char* ws = (char*)d_ws;
    u16* buf0 = (u16*)ws;                    // maskT [16][C][T], later comb bf16 [2][T][EC]  (33.5 MB)
    u16* xT   = (u16*)(ws + 33554432);       // [2][D][T]   (16.8 MB)
    u16* W1b  = (u16*)(ws + 50331648);       // [8][O1][D]  (8.4 MB)
    u16* W2b  = (u16*)(ws + 58720256);       // [8][D][O1]  (8.4 MB)
    u16* xe   = (u16*)(ws + 67108864);       // [16][C][D]  (33.5 MB) -- reused as yT [2][D][EC]
    u16* h    = (u16*)(ws + 100663296);      // [16][C][O1] (4.2 MB)
    u16* yT   = xe;

    // --- converts / transposes ---
    // xT[b][d][t] = x[b][t][d]
    transpose_conv<<<dim3(DD / 32, TT / 32, BB), 256, 0, stream>>>(
        x, (long)TT * DD, 0L, 1, (long)DD, xT, (long)DD * TT, (long)TT);
    // maskT[(b,e)][c][t] = mask[b][t][e][c]
    transpose_conv<<<dim3(CCv / 32, TT / 32, BB * EE), 256, 0, stream>>>(
        mask, (long)TT * EE * CCv, (long)CCv, EE, (long)EE * CCv,
        buf0, (long)CCv * TT, (long)TT);
    conv_cast<<<(int)((8L * OO1 * DD) / 1024), 256, 0, stream>>>(W1, W1b, 8L * OO1 * DD);
    conv_cast<<<(int)((8L * DD * OO1) / 1024), 256, 0, stream>>>(W2, W2b, 8L * DD * OO1);

    // --- GEMM1: xe[z][c][d] = sum_t maskT[z][c][t] * xT[b][d][t] ; M=512,N=2048,K=2048,Z=16
    mfma_gemm<0, 1><<<dim3(DD / 128, CCv / 128, 16), 256, 0, stream>>>(
        buf0, 2048, 1048576L, 0L, 1,
        xT,   2048, 4194304L, 0L, 8,
        xe,   2048, 1048576L, 0L, 1,
        nullptr, 0L, 1, CCv, DD, TT);

    // comb bf16 into buf0 (maskT dead after GEMM1; stream order serializes)
    conv_cast<<<(int)((2L * TT * EE * CCv) / 1024), 256, 0, stream>>>(
        comb, buf0, 2L * TT * EE * CCv);

    // --- GEMM2: h[z][c][o] = sum_d xe[z][c][d] * W1b[e][o][d] + b1[e], GELU ; M=512,N=256,K=2048
    mfma_gemm<1, 1><<<dim3(OO1 / 128, CCv / 128, 16), 256, 0, stream>>>(
        xe,  2048, 1048576L, 0L, 1,
        W1b, 2048, 0L, 524288L, 8,
        h,   256, 131072L, 0L, 1,
        b1, 256L, 8, CCv, OO1, DD);

    // --- GEMM3T: yT[b][d][e*512+c] = sum_i W2b[e][d][i] * h[z][c][i] + b2[d] ; M=2048,N=512,K=256
    mfma_gemm<3, 1><<<dim3(CCv / 128, DD / 128, 16), 256, 0, stream>>>(
        W2b, 256, 0L, 524288L, 8,
        h,   256, 131072L, 0L, 1,
        yT,  4096, 8388608L, 512L, 8,
        b2, 0L, 1, DD, CCv, OO1);

    // --- GEMM4: out[b][t][d] = sum_ec comb[b][t][ec] * yT[b][d][ec] ; M=2048,N=2048,K=4096,Z=2
    mfma_gemm<0, 0><<<dim3(DD / 128, TT / 128, BB), 256, 0, stream>>>(
        buf0, 4096, 8388608L, 0L, 1,
        yT,   4096, 8388608L, 0L, 1,
        out,  2048, 4194304L, 0L, 1,
        nullptr, 0L, 1, TT, DD, EE * CCv);
}

// Round 3
// 302.725 us; speedup vs baseline: 11.4702x; 1.0138x over previous
//
#include <hip/hip_runtime.h>
#include <math.h>

#define BB 2
#define TT 2048
#define DD 2048
#define EE 8
#define CCv 512
#define OO1 256

typedef unsigned short u16;
typedef __bf16 bf16x8 __attribute__((ext_vector_type(8)));
typedef float f32x4 __attribute__((ext_vector_type(4)));

__device__ __forceinline__ u16 f2bf(float f) {
    unsigned u = __float_as_uint(f);
    unsigned r = (u + 0x7fffu + ((u >> 16) & 1u)) >> 16;
    return (u16)r;
}

__device__ __forceinline__ void gload16(const void* g, void* s) {
    __builtin_amdgcn_global_load_lds(
        (const __attribute__((address_space(1))) void*)g,
        (__attribute__((address_space(3))) void*)s, 16, 0, 0);
}

// ---------------- fp32 -> bf16 straight convert (vectorized) ----------------
__global__ __launch_bounds__(256) void conv_cast(const float* __restrict__ in,
                                                 u16* __restrict__ out, long n) {
    long i = ((long)blockIdx.x * 256 + threadIdx.x) * 4;
    float4 v = *(const float4*)&in[i];
    ushort4 o; o.x = f2bf(v.x); o.y = f2bf(v.y); o.z = f2bf(v.z); o.w = f2bf(v.w);
    *(ushort4*)&out[i] = o;
}

// ---------------- tiled transpose + convert: out[z][c][t] = in[z][t][c] ----------------
__global__ __launch_bounds__(256) void transpose_conv(
    const float* __restrict__ in, long inHi, long inLo, int modZ, long sIn,
    u16* __restrict__ out, long outZ, long sOut)
{
    __shared__ float tile[32][33];
    const int z = blockIdx.z;
    const float* ib = in + (long)(z / modZ) * inHi + (long)(z % modZ) * inLo;
    u16* ob = out + (long)z * outZ;
    const int t0 = blockIdx.y * 32, c0 = blockIdx.x * 32;
    const int tid = threadIdx.x;
    const int r = tid >> 3, c4 = (tid & 7) * 4;

    float4 v = *(const float4*)&ib[(long)(t0 + r) * sIn + c0 + c4];
    tile[r][c4 + 0] = v.x; tile[r][c4 + 1] = v.y;
    tile[r][c4 + 2] = v.z; tile[r][c4 + 3] = v.w;
    __syncthreads();

    const int oc = tid >> 3, t4 = (tid & 7) * 4;
    ushort4 o;
    o.x = f2bf(tile[t4 + 0][oc]);
    o.y = f2bf(tile[t4 + 1][oc]);
    o.z = f2bf(tile[t4 + 2][oc]);
    o.w = f2bf(tile[t4 + 3][oc]);
    *(ushort4*)&ob[(long)(c0 + oc) * sOut + t0 + t4] = o;
}

// ---------------- small 128x128 m97-structure GEMM (GEMM2 / GEMM3) ----------------
// C[z][m][n] = sum_k A[z][m][k] * B[z][n][k]
// EPI: 1 col-bias + exact GELU, 3 row-bias. Output bf16.
template<int EPI>
__global__ __launch_bounds__(256)
void mfma_gemm(const u16* __restrict__ A, long ldA, long aHi, long aLo, int modA,
               const u16* __restrict__ B, long ldB, long bHi, long bLo, int modB,
               void* __restrict__ Cout, long ldC, long cHi, long cLo, int modC,
               const float* __restrict__ bias, long biasLo, int modBias,
               int M, int N, int K)
{
    __shared__ __align__(16) char smem[32768];
    char* smA = smem;
    char* smB = smem + 16384;

    const int z = blockIdx.z;
    const char* Ab = (const char*)(A + (long)(z / modA) * aHi + (long)(z % modA) * aLo);
    const char* Bb = (const char*)(B + (long)(z / modB) * bHi + (long)(z % modB) * bLo);
    const long ldAb = ldA * 2, ldBb = ldB * 2;

    const int m0 = blockIdx.y * 128, n0 = blockIdx.x * 128;
    const int tid = threadIdx.x;
    const int l = tid & 63;
    const int w = tid >> 6;
    const int wm = w >> 1, wn = w & 1;

    const int srow = l >> 3;
    const int schunk = (l & 7) ^ srow;
    const int frow = l & 15;
    const int fgrp = l >> 4;
    const int fch0 = fgrp ^ (l & 7);

    int aoff[4], boff[4];
#pragma unroll
    for (int i = 0; i < 4; ++i) {
        aoff[i] = (wm * 64 + i * 16 + frow) * 128 + fch0 * 16;
        boff[i] = (wn * 64 + i * 16 + frow) * 128 + fch0 * 16;
    }

    f32x4 acc[4][4];
    const f32x4 zero4 = {0.f, 0.f, 0.f, 0.f};
#pragma unroll
    for (int i = 0; i < 4; ++i)
#pragma unroll
        for (int j = 0; j < 4; ++j) acc[i][j] = zero4;

    const long sgo = (long)schunk * 16;

    for (int k0 = 0; k0 < K; k0 += 64) {
        const long kb = (long)k0 * 2;
#pragma unroll
        for (int j = 0; j < 4; ++j) {
            const int rr = (j * 4 + w) * 8 + srow;
            gload16(Ab + (long)(m0 + rr) * ldAb + kb + sgo, smA + (j * 4 + w) * 1024);
            gload16(Bb + (long)(n0 + rr) * ldBb + kb + sgo, smB + (j * 4 + w) * 1024);
        }
        __syncthreads();
#pragma unroll
        for (int kk = 0; kk < 2; ++kk) {
            const int kx = kk * 64;
            bf16x8 af[4], bfr[4];
#pragma unroll
            for (int i = 0; i < 4; ++i) af[i] = *(const bf16x8*)(smA + (aoff[i] ^ kx));
#pragma unroll
            for (int i = 0; i < 4; ++i) bfr[i] = *(const bf16x8*)(smB + (boff[i] ^ kx));
#pragma unroll
            for (int mi = 0; mi < 4; ++mi)
#pragma unroll
                for (int ni = 0; ni < 4; ++ni)
                    acc[mi][ni] = __builtin_amdgcn_mfma_f32_16x16x32_bf16(
                        af[mi], bfr[ni], acc[mi][ni], 0, 0, 0);
        }
        __syncthreads();
    }

    const long cbase = (long)(z / modC) * cHi + (long)(z % modC) * cLo;
    const float* biasB = bias + (long)(z % modBias) * biasLo;
#pragma unroll
    for (int mi = 0; mi < 4; ++mi) {
#pragma unroll
        for (int ni = 0; ni < 4; ++ni) {
            const int col = n0 + wn * 64 + ni * 16 + frow;
            const int rowb = m0 + wm * 64 + mi * 16 + fgrp * 4;
#pragma unroll
            for (int r = 0; r < 4; ++r) {
                float v = acc[mi][ni][r];
                const int row = rowb + r;
                if (EPI == 1) {
                    v += biasB[col];
                    v = 0.5f * v * (1.0f + erff(v * 0.70710678118654752f));
                } else {
                    v += biasB[row];
                }
                ((u16*)Cout)[cbase + (long)row * ldC + col] = f2bf(v);
            }
        }
    }
}

// ---------------- BIG pipelined GEMM: BM=256, BN=128, BK=64, 8 waves ----------------
// 3-buffer LDS (144 KB), staging 2 tiles ahead (never into a live buffer),
// counted s_waitcnt vmcnt(6) once per K-tile, raw s_barrier (no compiler drain),
// 4 phases/tile with setprio(1) around the MFMA cluster.
// C[z][m][n] = sum_k A[z][m][k] * B[z][n][k]; OUTBF: 1 -> bf16 out, 0 -> fp32.
template<int OUTBF>
__global__ __launch_bounds__(512, 2)
void mfma_gemm_big(const u16* __restrict__ A, long ldA, long aHi, long aLo, int modA,
                   const u16* __restrict__ B, long ldB, long bHi, long bLo, int modB,
                   void* __restrict__ Cout, long ldC, long cHi, long cLo, int modC,
                   int M, int N, int K)
{
    __shared__ __align__(16) char smem[147456];   // 3 x (A 32KB + B 16KB)

    const int z = blockIdx.z;
    const char* Ab = (const char*)(A + (long)(z / modA) * aHi + (long)(z % modA) * aLo);
    const char* Bb = (const char*)(B + (long)(z / modB) * bHi + (long)(z % modB) * bLo);
    const long ldAb = ldA * 2, ldBb = ldB * 2;

    const int m0 = blockIdx.y * 256, n0 = blockIdx.x * 128;
    const int tid = threadIdx.x;
    const int l = tid & 63;
    const int w = tid >> 6;           // 0..7
    const int wm = w >> 2, wn = w & 3;

    const int srow = l >> 3;
    const int schunk = (l & 7) ^ srow;       // pre-swizzled source chunk (T2)
    const long sgo = (long)schunk * 16;
    const int frow = l & 15;
    const int fgrp = l >> 4;
    const int fsw = (fgrp ^ (l & 7)) * 16;   // swizzled read chunk, kk=0

    // stage tile kt (K-offset kt*128 bytes) into buffer bsel
    auto stageA = [&](int kt, int bsel, int j) {
        const int rr = (j * 8 + w) * 8 + srow;            // rows 0..255
        gload16(Ab + (long)(m0 + rr) * ldAb + (long)kt * 128 + sgo,
                smem + bsel * 49152 + (j * 8 + w) * 1024);
    };
    auto stageB = [&](int kt, int bsel, int j) {
        const int rr = (j * 8 + w) * 8 + srow;            // rows 0..127
        gload16(Bb + (long)(n0 + rr) * ldBb + (long)kt * 128 + sgo,
                smem + bsel * 49152 + 32768 + (j * 8 + w) * 1024);
    };

    f32x4 acc[8][2];
    const f32x4 zero4 = {0.f, 0.f, 0.f, 0.f};
#pragma unroll
    for (int i = 0; i < 8; ++i) { acc[i][0] = zero4; acc[i][1] = zero4; }

    // prologue: stage tiles 0 and 1 (12 loads), keep tile 1 in flight
#pragma unroll
    for (int j = 0; j < 4; ++j) stageA(0, 0, j);
#pragma unroll
    for (int j = 0; j < 2; ++j) stageB(0, 0, j);
#pragma unroll
    for (int j = 0; j < 4; ++j) stageA(1, 1, j);
#pragma unroll
    for (int j = 0; j < 2; ++j) stageB(1, 1, j);
    asm volatile("s_waitcnt vmcnt(6)" ::: "memory");
    __builtin_amdgcn_s_barrier();

    const int NT = K >> 6;
    int bc = 0;        // buffer holding tile kt
    int sc = 2;        // buffer receiving tile kt+2
    for (int kt = 0; kt < NT; ++kt) {
        const char* bufA = smem + bc * 49152;
        const char* bufB = bufA + 32768;
        const bool pf = (kt + 2) < NT;
        const int kpf = kt + 2;
        bf16x8 af[4][2];
#pragma unroll
        for (int p = 0; p < 4; ++p) {
            const int qm = p >> 1, qn = p & 1;
            if (qn == 0) {
#pragma unroll
                for (int mi = 0; mi < 4; ++mi) {
                    const int ab = (wm * 128 + (qm * 4 + mi) * 16 + frow) * 128 + fsw;
                    af[mi][0] = *(const bf16x8*)(bufA + ab);
                    af[mi][1] = *(const bf16x8*)(bufA + (ab ^ 64));
                }
            }
            bf16x8 bfr[2];
            const int bb0 = (wn * 32 + qn * 16 + frow) * 128 + fsw;
            bfr[0] = *(const bf16x8*)(bufB + bb0);
            bfr[1] = *(const bf16x8*)(bufB + (bb0 ^ 64));
            if (pf) {
                if (p == 0)      { stageA(kpf, sc, 0); stageA(kpf, sc, 1); }
                else if (p == 1) { stageA(kpf, sc, 2); stageA(kpf, sc, 3); }
                else if (p == 2) { stageB(kpf, sc, 0); }
                else             { stageB(kpf, sc, 1); }
            }
            __builtin_amdgcn_s_barrier();
            asm volatile("s_waitcnt lgkmcnt(0)" ::: "memory");
            __builtin_amdgcn_s_setprio(1);
#pragma unroll
            for (int mi = 0; mi < 4; ++mi) {
                acc[qm * 4 + mi][qn] = __builtin_amdgcn_mfma_f32_16x16x32_bf16(
                    af[mi][0], bfr[0], acc[qm * 4 + mi][qn], 0, 0, 0);
                acc[qm * 4 + mi][qn] = __builtin_amdgcn_mfma_f32_16x16x32_bf16(
                    af[mi][1], bfr[1], acc[qm * 4 + mi][qn], 0, 0, 0);
            }
            __builtin_amdgcn_s_setprio(0);
            __builtin_amdgcn_s_barrier();
        }
        if (pf) { asm volatile("s_waitcnt vmcnt(6)" ::: "memory"); }
        else    { asm volatile("s_waitcnt vmcnt(0)" ::: "memory"); }
        __builtin_amdgcn_s_barrier();
        bc = (bc == 2) ? 0 : bc + 1;
        sc = (sc == 2) ? 0 : sc + 1;
    }

    // epilogue
    const long cbase = (long)(z / modC) * cHi + (long)(z % modC) * cLo;
#pragma unroll
    for (int Mi = 0; Mi < 8; ++Mi) {
#pragma unroll
        for (int ni = 0; ni < 2; ++ni) {
            const int col = n0 + wn * 32 + ni * 16 + frow;
            const int rowb = m0 + wm * 128 + Mi * 16 + fgrp * 4;
#pragma unroll
            for (int r = 0; r < 4; ++r) {
                const float v = acc[Mi][ni][r];
                const long idx = cbase + (long)(rowb + r) * ldC + col;
                if (OUTBF) ((u16*)Cout)[idx] = f2bf(v);
                else       ((float*)Cout)[idx] = v;
            }
        }
    }
}

extern "C" void kernel_launch(void* const* d_in, const int* in_sizes, int n_in,
                              void* d_out, int out_size, void* d_ws, size_t ws_size,
                              hipStream_t stream) {
    const float* x    = (const float*)d_in[0];
    const float* mask = (const float*)d_in[1];
    const float* comb = (const float*)d_in[2];
    const float* W1   = (const float*)d_in[3];
    const float* b1   = (const float*)d_in[4];
    const float* W2   = (const float*)d_in[5];
    const float* b2   = (const float*)d_in[6];
    float* out = (float*)d_out;

    char* ws = (char*)d_ws;
    u16* buf0 = (u16*)ws;                    // maskT [16][C][T] -> comb bf16 [2][T][EC]
    u16* xT   = (u16*)(ws + 33554432);       // [2][D][T]
    u16* W1b  = (u16*)(ws + 50331648);       // [8][O1][D]
    u16* W2b  = (u16*)(ws + 58720256);       // [8][D][O1]
    u16* xe   = (u16*)(ws + 67108864);       // [16][C][D] -> yT [2][D][EC]
    u16* h    = (u16*)(ws + 100663296);      // [16][C][O1]
    u16* yT   = xe;

    transpose_conv<<<dim3(DD / 32, TT / 32, BB), 256, 0, stream>>>(
        x, (long)TT * DD, 0L, 1, (long)DD, xT, (long)DD * TT, (long)TT);
    transpose_conv<<<dim3(CCv / 32, TT / 32, BB * EE), 256, 0, stream>>>(
        mask, (long)TT * EE * CCv, (long)CCv, EE, (long)EE * CCv,
        buf0, (long)CCv * TT, (long)TT);
    conv_cast<<<(int)((8L * OO1 * DD) / 1024), 256, 0, stream>>>(W1, W1b, 8L * OO1 * DD);
    conv_cast<<<(int)((8L * DD * OO1) / 1024), 256, 0, stream>>>(W2, W2b, 8L * DD * OO1);

    // GEMM1: xe[z][c][d] = sum_t maskT[z][c][t] * xT[b][d][t] ; M=512,N=2048,K=2048,Z=16
    mfma_gemm_big<1><<<dim3(DD / 128, CCv / 256, 16), 512, 0, stream>>>(
        buf0, 2048, 1048576L, 0L, 1,
        xT,   2048, 4194304L, 0L, 8,
        xe,   2048, 1048576L, 0L, 1,
        CCv, DD, TT);

    conv_cast<<<(int)((2L * TT * EE * CCv) / 1024), 256, 0, stream>>>(
        comb, buf0, 2L * TT * EE * CCv);

    // GEMM2: h = GELU(xe . W1^T + b1) ; M=512,N=256,K=2048,Z=16
    mfma_gemm<1><<<dim3(OO1 / 128, CCv / 128, 16), 256, 0, stream>>>(
        xe,  2048, 1048576L, 0L, 1,
        W1b, 2048, 0L, 524288L, 8,
        h,   256, 131072L, 0L, 1,
        b1, 256L, 8, CCv, OO1, DD);

    // GEMM3T: yT[b][d][e*512+c] = W2 . h^T + b2 ; M=2048,N=512,K=256,Z=16
    mfma_gemm<3><<<dim3(CCv / 128, DD / 128, 16), 256, 0, stream>>>(
        W2b, 256, 0L, 524288L, 8,
        h,   256, 131072L, 0L, 1,
        yT,  4096, 8388608L, 512L, 8,
        b2, 0L, 1, DD, CCv, OO1);

    // GEMM4: out[b][t][d] = sum_ec comb[b][t][ec] * yT[b][d][ec] ; M=2048,N=2048,K=4096,Z=2
    mfma_gemm_big<0><<<dim3(DD / 128, TT / 256, BB), 512, 0, stream>>>(
        buf0, 4096, 8388608L, 0L, 1,
        yT,   4096, 8388608L, 0L, 1,
        out,  2048, 4194304L, 0L, 1,
        TT, DD, EE * CCv);
}

// Round 4
// 277.152 us; speedup vs baseline: 12.5286x; 1.0923x over previous
//
#include <hip/hip_runtime.h>
#include <math.h>

#define BB 2
#define TT 2048
#define DD 2048
#define EE 8
#define CCv 512
#define OO1 256

typedef unsigned short u16;
typedef __bf16 bf16x8 __attribute__((ext_vector_type(8)));
typedef float f32x4 __attribute__((ext_vector_type(4)));

__device__ __forceinline__ u16 f2bf(float f) {
    unsigned u = __float_as_uint(f);
    unsigned r = (u + 0x7fffu + ((u >> 16) & 1u)) >> 16;
    return (u16)r;
}

__device__ __forceinline__ void gload16(const void* g, void* s) {
    __builtin_amdgcn_global_load_lds(
        (const __attribute__((address_space(1))) void*)g,
        (__attribute__((address_space(3))) void*)s, 16, 0, 0);
}

// ---------------- fp32 -> bf16 straight convert (vectorized) ----------------
__global__ __launch_bounds__(256) void conv_cast(const float* __restrict__ in,
                                                 u16* __restrict__ out, long n) {
    long i = ((long)blockIdx.x * 256 + threadIdx.x) * 4;
    float4 v = *(const float4*)&in[i];
    ushort4 o; o.x = f2bf(v.x); o.y = f2bf(v.y); o.z = f2bf(v.z); o.w = f2bf(v.w);
    *(ushort4*)&out[i] = o;
}

// ---------------- tiled transpose + convert: out[z][c][t] = in[z][t][c] ----------------
__global__ __launch_bounds__(256) void transpose_conv(
    const float* __restrict__ in, long inHi, long inLo, int modZ, long sIn,
    u16* __restrict__ out, long outZ, long sOut)
{
    __shared__ float tile[32][33];
    const int z = blockIdx.z;
    const float* ib = in + (long)(z / modZ) * inHi + (long)(z % modZ) * inLo;
    u16* ob = out + (long)z * outZ;
    const int t0 = blockIdx.y * 32, c0 = blockIdx.x * 32;
    const int tid = threadIdx.x;
    const int r = tid >> 3, c4 = (tid & 7) * 4;

    float4 v = *(const float4*)&ib[(long)(t0 + r) * sIn + c0 + c4];
    tile[r][c4 + 0] = v.x; tile[r][c4 + 1] = v.y;
    tile[r][c4 + 2] = v.z; tile[r][c4 + 3] = v.w;
    __syncthreads();

    const int oc = tid >> 3, t4 = (tid & 7) * 4;
    ushort4 o;
    o.x = f2bf(tile[t4 + 0][oc]);
    o.y = f2bf(tile[t4 + 1][oc]);
    o.z = f2bf(tile[t4 + 2][oc]);
    o.w = f2bf(tile[t4 + 3][oc]);
    *(ushort4*)&ob[(long)(c0 + oc) * sOut + t0 + t4] = o;
}

// ---------------- small 128x128 m97-structure GEMM (GEMM2 / GEMM3) ----------------
// C[z][m][n] = sum_k A[z][m][k] * B[z][n][k]
// EPI: 1 col-bias + exact GELU, 3 row-bias. Output bf16.
template<int EPI>
__global__ __launch_bounds__(256)
void mfma_gemm(const u16* __restrict__ A, long ldA, long aHi, long aLo, int modA,
               const u16* __restrict__ B, long ldB, long bHi, long bLo, int modB,
               void* __restrict__ Cout, long ldC, long cHi, long cLo, int modC,
               const float* __restrict__ bias, long biasLo, int modBias,
               int M, int N, int K)
{
    __shared__ __align__(16) char smem[32768];
    char* smA = smem;
    char* smB = smem + 16384;

    const int z = blockIdx.z;
    const char* Ab = (const char*)(A + (long)(z / modA) * aHi + (long)(z % modA) * aLo);
    const char* Bb = (const char*)(B + (long)(z / modB) * bHi + (long)(z % modB) * bLo);
    const long ldAb = ldA * 2, ldBb = ldB * 2;

    const int m0 = blockIdx.y * 128, n0 = blockIdx.x * 128;
    const int tid = threadIdx.x;
    const int l = tid & 63;
    const int w = tid >> 6;
    const int wm = w >> 1, wn = w & 1;

    const int srow = l >> 3;
    const int schunk = (l & 7) ^ srow;
    const int frow = l & 15;
    const int fgrp = l >> 4;
    const int fch0 = fgrp ^ (l & 7);

    int aoff[4], boff[4];
#pragma unroll
    for (int i = 0; i < 4; ++i) {
        aoff[i] = (wm * 64 + i * 16 + frow) * 128 + fch0 * 16;
        boff[i] = (wn * 64 + i * 16 + frow) * 128 + fch0 * 16;
    }

    f32x4 acc[4][4];
    const f32x4 zero4 = {0.f, 0.f, 0.f, 0.f};
#pragma unroll
    for (int i = 0; i < 4; ++i)
#pragma unroll
        for (int j = 0; j < 4; ++j) acc[i][j] = zero4;

    const long sgo = (long)schunk * 16;

    for (int k0 = 0; k0 < K; k0 += 64) {
        const long kb = (long)k0 * 2;
#pragma unroll
        for (int j = 0; j < 4; ++j) {
            const int rr = (j * 4 + w) * 8 + srow;
            gload16(Ab + (long)(m0 + rr) * ldAb + kb + sgo, smA + (j * 4 + w) * 1024);
            gload16(Bb + (long)(n0 + rr) * ldBb + kb + sgo, smB + (j * 4 + w) * 1024);
        }
        __syncthreads();
#pragma unroll
        for (int kk = 0; kk < 2; ++kk) {
            const int kx = kk * 64;
            bf16x8 af[4], bfr[4];
#pragma unroll
            for (int i = 0; i < 4; ++i) af[i] = *(const bf16x8*)(smA + (aoff[i] ^ kx));
#pragma unroll
            for (int i = 0; i < 4; ++i) bfr[i] = *(const bf16x8*)(smB + (boff[i] ^ kx));
#pragma unroll
            for (int mi = 0; mi < 4; ++mi)
#pragma unroll
                for (int ni = 0; ni < 4; ++ni)
                    acc[mi][ni] = __builtin_amdgcn_mfma_f32_16x16x32_bf16(
                        af[mi], bfr[ni], acc[mi][ni], 0, 0, 0);
        }
        __syncthreads();
    }

    const long cbase = (long)(z / modC) * cHi + (long)(z % modC) * cLo;
    const float* biasB = bias + (long)(z % modBias) * biasLo;
#pragma unroll
    for (int mi = 0; mi < 4; ++mi) {
#pragma unroll
        for (int ni = 0; ni < 4; ++ni) {
            const int col = n0 + wn * 64 + ni * 16 + frow;
            const int rowb = m0 + wm * 64 + mi * 16 + fgrp * 4;
#pragma unroll
            for (int r = 0; r < 4; ++r) {
                float v = acc[mi][ni][r];
                const int row = rowb + r;
                if (EPI == 1) {
                    v += biasB[col];
                    v = 0.5f * v * (1.0f + erff(v * 0.70710678118654752f));
                } else {
                    v += biasB[row];
                }
                ((u16*)Cout)[cbase + (long)row * ldC + col] = f2bf(v);
            }
        }
    }
}

// ---------------- BIG pipelined GEMM: BM=256, BN=128, BK=64, 8 waves ----------------
// 3-buffer LDS rotation (144 KB): staging always lands 2 tiles ahead in a buffer
// nobody reads -> ONE raw s_barrier + ONE counted vmcnt(6) per K-tile (never 0 in
// the main loop). Wave tile 64x64 (4M x 2N). 32 MFMAs per barrier per wave.
// C[z][m][n] = sum_k A[z][m][k] * B[z][n][k]; OUTBF: 1 -> bf16 out, 0 -> fp32.
template<int OUTBF>
__global__ __launch_bounds__(512, 2)
void mfma_gemm_big(const u16* __restrict__ A, long ldA, long aHi, long aLo, int modA,
                   const u16* __restrict__ B, long ldB, long bHi, long bLo, int modB,
                   void* __restrict__ Cout, long ldC, long cHi, long cLo, int modC,
                   int M, int N, int K)
{
    __shared__ __align__(16) char smem[147456];   // 3 x (A 32KB + B 16KB)

    const int z = blockIdx.z;
    const char* Ab = (const char*)(A + (long)(z / modA) * aHi + (long)(z % modA) * aLo);
    const char* Bb = (const char*)(B + (long)(z / modB) * bHi + (long)(z % modB) * bLo);
    const long ldAb = ldA * 2, ldBb = ldB * 2;

    const int m0 = blockIdx.y * 256, n0 = blockIdx.x * 128;
    const int tid = threadIdx.x;
    const int l = tid & 63;
    const int w = tid >> 6;           // 0..7
    const int wm = w >> 1, wn = w & 1;   // 4M x 2N -> wave tile 64x64

    const int srow = l >> 3;
    const int schunk = (l & 7) ^ srow;       // pre-swizzled source chunk (T2)
    const long sgo = (long)schunk * 16;
    const int frow = l & 15;
    const int fgrp = l >> 4;
    const int fsw = (fgrp ^ (l & 7)) * 16;   // swizzled read chunk, kk=0

    auto stageA = [&](int kt, int bsel, int j) {
        const int rr = (j * 8 + w) * 8 + srow;            // rows 0..255
        gload16(Ab + (long)(m0 + rr) * ldAb + (long)kt * 128 + sgo,
                smem + bsel * 49152 + (j * 8 + w) * 1024);
    };
    auto stageB = [&](int kt, int bsel, int j) {
        const int rr = (j * 8 + w) * 8 + srow;            // rows 0..127
        gload16(Bb + (long)(n0 + rr) * ldBb + (long)kt * 128 + sgo,
                smem + bsel * 49152 + 32768 + (j * 8 + w) * 1024);
    };

    f32x4 acc[4][4];
    const f32x4 zero4 = {0.f, 0.f, 0.f, 0.f};
#pragma unroll
    for (int i = 0; i < 4; ++i)
#pragma unroll
        for (int j = 0; j < 4; ++j) acc[i][j] = zero4;

    // prologue: stage tiles 0 and 1; wait for tile 0 only (6 newest stay in flight)
#pragma unroll
    for (int j = 0; j < 4; ++j) stageA(0, 0, j);
#pragma unroll
    for (int j = 0; j < 2; ++j) stageB(0, 0, j);
#pragma unroll
    for (int j = 0; j < 4; ++j) stageA(1, 1, j);
#pragma unroll
    for (int j = 0; j < 2; ++j) stageB(1, 1, j);
    asm volatile("s_waitcnt vmcnt(6)" ::: "memory");
    __builtin_amdgcn_s_barrier();

    const int NT = K >> 6;
    int bc = 0;        // buffer holding tile kt
    int sc = 2;        // buffer receiving tile kt+2
    for (int kt = 0; kt < NT; ++kt) {
        const char* bufA = smem + bc * 49152;
        const char* bufB = bufA + 32768;
        const bool pf = (kt + 2) < NT;

        // issue prefetch early (T14): 6 global_load_lds into the idle buffer
        if (pf) {
            const int kpf = kt + 2;
            stageA(kpf, sc, 0); stageA(kpf, sc, 1);
            stageA(kpf, sc, 2); stageA(kpf, sc, 3);
            stageB(kpf, sc, 0); stageB(kpf, sc, 1);
        }

        // ds_read all fragments for this tile (compiler inserts fine lgkmcnt)
        bf16x8 af[4][2], bfr[4][2];
#pragma unroll
        for (int mi = 0; mi < 4; ++mi) {
            const int ab = (wm * 64 + mi * 16 + frow) * 128 + fsw;
            af[mi][0] = *(const bf16x8*)(bufA + ab);
            af[mi][1] = *(const bf16x8*)(bufA + (ab ^ 64));
        }
#pragma unroll
        for (int ni = 0; ni < 4; ++ni) {
            const int bb = (wn * 64 + ni * 16 + frow) * 128 + fsw;
            bfr[ni][0] = *(const bf16x8*)(bufB + bb);
            bfr[ni][1] = *(const bf16x8*)(bufB + (bb ^ 64));
        }

        __builtin_amdgcn_s_setprio(1);
#pragma unroll
        for (int kk = 0; kk < 2; ++kk)
#pragma unroll
            for (int mi = 0; mi < 4; ++mi)
#pragma unroll
                for (int ni = 0; ni < 4; ++ni)
                    acc[mi][ni] = __builtin_amdgcn_mfma_f32_16x16x32_bf16(
                        af[mi][kk], bfr[ni][kk], acc[mi][ni], 0, 0, 0);
        __builtin_amdgcn_s_setprio(0);

        // counted wait: ensure tile kt+1 has landed; tile kt+2's 6 stay in flight
        if (pf) { asm volatile("s_waitcnt vmcnt(6)" ::: "memory"); }
        else    { asm volatile("s_waitcnt vmcnt(0)" ::: "memory"); }
        __builtin_amdgcn_s_barrier();

        bc = (bc == 2) ? 0 : bc + 1;
        sc = (sc == 2) ? 0 : sc + 1;
    }

    // epilogue
    const long cbase = (long)(z / modC) * cHi + (long)(z % modC) * cLo;
#pragma unroll
    for (int mi = 0; mi < 4; ++mi) {
#pragma unroll
        for (int ni = 0; ni < 4; ++ni) {
            const int col = n0 + wn * 64 + ni * 16 + frow;
            const int rowb = m0 + wm * 64 + mi * 16 + fgrp * 4;
#pragma unroll
            for (int r = 0; r < 4; ++r) {
                const float v = acc[mi][ni][r];
                const long idx = cbase + (long)(rowb + r) * ldC + col;
                if (OUTBF) ((u16*)Cout)[idx] = f2bf(v);
                else       ((float*)Cout)[idx] = v;
            }
        }
    }
}

extern "C" void kernel_launch(void* const* d_in, const int* in_sizes, int n_in,
                              void* d_out, int out_size, void* d_ws, size_t ws_size,
                              hipStream_t stream) {
    const float* x    = (const float*)d_in[0];
    const float* mask = (const float*)d_in[1];
    const float* comb = (const float*)d_in[2];
    const float* W1   = (const float*)d_in[3];
    const float* b1   = (const float*)d_in[4];
    const float* W2   = (const float*)d_in[5];
    const float* b2   = (const float*)d_in[6];
    float* out = (float*)d_out;

    char* ws = (char*)d_ws;
    u16* buf0 = (u16*)ws;                    // maskT [16][C][T] -> comb bf16 [2][T][EC]
    u16* xT   = (u16*)(ws + 33554432);       // [2][D][T]
    u16* W1b  = (u16*)(ws + 50331648);       // [8][O1][D]
    u16* W2b  = (u16*)(ws + 58720256);       // [8][D][O1]
    u16* xe   = (u16*)(ws + 67108864);       // [16][C][D] -> yT [2][D][EC]
    u16* h    = (u16*)(ws + 100663296);      // [16][C][O1]
    u16* yT   = xe;

    transpose_conv<<<dim3(DD / 32, TT / 32, BB), 256, 0, stream>>>(
        x, (long)TT * DD, 0L, 1, (long)DD, xT, (long)DD * TT, (long)TT);
    transpose_conv<<<dim3(CCv / 32, TT / 32, BB * EE), 256, 0, stream>>>(
        mask, (long)TT * EE * CCv, (long)CCv, EE, (long)EE * CCv,
        buf0, (long)CCv * TT, (long)TT);
    conv_cast<<<(int)((8L * OO1 * DD) / 1024), 256, 0, stream>>>(W1, W1b, 8L * OO1 * DD);
    conv_cast<<<(int)((8L * DD * OO1) / 1024), 256, 0, stream>>>(W2, W2b, 8L * DD * OO1);

    // GEMM1: xe[z][c][d] = sum_t maskT[z][c][t] * xT[b][d][t] ; M=512,N=2048,K=2048,Z=16
    mfma_gemm_big<1><<<dim3(DD / 128, CCv / 256, 16), 512, 0, stream>>>(
        buf0, 2048, 1048576L, 0L, 1,
        xT,   2048, 4194304L, 0L, 8,
        xe,   2048, 1048576L, 0L, 1,
        CCv, DD, TT);

    conv_cast<<<(int)((2L * TT * EE * CCv) / 1024), 256, 0, stream>>>(
        comb, buf0, 2L * TT * EE * CCv);

    // GEMM2: h = GELU(xe . W1^T + b1) ; M=512,N=256,K=2048,Z=16
    mfma_gemm<1><<<dim3(OO1 / 128, CCv / 128, 16), 256, 0, stream>>>(
        xe,  2048, 1048576L, 0L, 1,
        W1b, 2048, 0L, 524288L, 8,
        h,   256, 131072L, 0L, 1,
        b1, 256L, 8, CCv, OO1, DD);

    // GEMM3T: yT[b][d][e*512+c] = W2 . h^T + b2 ; M=2048,N=512,K=256,Z=16
    mfma_gemm<3><<<dim3(CCv / 128, DD / 128, 16), 256, 0, stream>>>(
        W2b, 256, 0L, 524288L, 8,
        h,   256, 131072L, 0L, 1,
        yT,  4096, 8388608L, 512L, 8,
        b2, 0L, 1, DD, CCv, OO1);

    // GEMM4: out[b][t][d] = sum_ec comb[b][t][ec] * yT[b][d][ec] ; M=2048,N=2048,K=4096,Z=2
    mfma_gemm_big<0><<<dim3(DD / 128, TT / 256, BB), 512, 0, stream>>>(
        buf0, 4096, 8388608L, 0L, 1,
        yT,   4096, 8388608L, 0L, 1,
        out,  2048, 4194304L, 0L, 1,
        TT, DD, EE * CCv);
}